// Round 1
// baseline (2587.608 us; speedup 1.0000x reference)
//
#include <hip/hip_runtime.h>
#include <hip/hip_bf16.h>
#include <math.h>

// ---------------- Degree / normalization ----------------

__global__ void deg_count(const int* __restrict__ dst, float* __restrict__ deg, int E) {
    int e = blockIdx.x * 256 + threadIdx.x;
    if (e < E) atomicAdd(&deg[dst[e]], 1.0f);
}

__global__ void deg_inv(float* __restrict__ deg, int N) {
    int n = blockIdx.x * 256 + threadIdx.x;
    if (n < N) deg[n] = rsqrtf(deg[n] + 1.0f);   // +1 self-loop; always > 0
}

// ---------------- Tiny transpose of lin2_w [128][10] -> [10][128] ----------------

__global__ void transpose_w2(const float* __restrict__ W, float* __restrict__ Wt) {
    for (int i = threadIdx.x; i < 1280; i += blockDim.x) {
        int k = i / 10, c = i % 10;
        Wt[c * 128 + k] = W[i];
    }
}

// ---------------- GEMM: Y[n][d] = sum_k X[n][k] * W[k][d] (+bias, relu) ----------------
// K = Dout = 128 fixed. W staged fully in LDS (64KB), 8 rows of X per block.

template<bool BIAS, bool RELU>
__global__ __launch_bounds__(256) void gemm128(const float* __restrict__ X,
                                               const float* __restrict__ W,
                                               const float* __restrict__ bias,
                                               float* __restrict__ Y, int N) {
    __shared__ float Wl[128 * 128];      // 64 KB
    __shared__ float Xl[8][132];         // +4 pad: breaks 8-way bank alias on Xl[r][k]

    int tid = threadIdx.x;
    // stage W (coalesced float4)
    {
        const float4* Wg = (const float4*)W;
        float4* Wl4 = (float4*)Wl;
        #pragma unroll
        for (int i = 0; i < 16; ++i) Wl4[tid + i * 256] = Wg[tid + i * 256];
    }
    int n0 = blockIdx.x * 8;
    // stage 8 rows of X
    {
        int r = tid >> 5, k4 = tid & 31;
        if (n0 + r < N)
            *(float4*)&Xl[r][k4 * 4] = *(const float4*)&X[(size_t)(n0 + r) * 128 + k4 * 4];
    }
    __syncthreads();

    int r = tid >> 5, c4 = tid & 31;
    float4 acc = {0.f, 0.f, 0.f, 0.f};
    const float4* Wrow = (const float4*)Wl;   // [k][c4]
    #pragma unroll 8
    for (int k = 0; k < 128; ++k) {
        float xv = Xl[r][k];
        float4 w = Wrow[k * 32 + c4];
        acc.x += xv * w.x; acc.y += xv * w.y; acc.z += xv * w.z; acc.w += xv * w.w;
    }
    if (n0 + r < N) {
        if (BIAS) {
            float4 b = ((const float4*)bias)[c4];
            acc.x += b.x; acc.y += b.y; acc.z += b.z; acc.w += b.w;
        }
        if (RELU) {
            acc.x = fmaxf(acc.x, 0.f); acc.y = fmaxf(acc.y, 0.f);
            acc.z = fmaxf(acc.z, 0.f); acc.w = fmaxf(acc.w, 0.f);
        }
        ((float4*)Y)[(size_t)(n0 + r) * 32 + c4] = acc;
    }
}

// ---------------- Edge scatter: AGG[dst] += H[src] * dinv[src]*dinv[dst] ----------------
// 32 threads per edge, float4 gather, 4 scalar atomics each.

__global__ __launch_bounds__(256) void scatter_edges(const float* __restrict__ H,
                                                     const int* __restrict__ src,
                                                     const int* __restrict__ dst,
                                                     const float* __restrict__ dinv,
                                                     float* __restrict__ AGG, int E) {
    long long idx = (long long)blockIdx.x * 256 + threadIdx.x;
    if (idx >= (long long)E * 32) return;
    int e  = (int)(idx >> 5);
    int f4 = (int)(idx & 31);
    int s = src[e], d = dst[e];
    float nrm = dinv[s] * dinv[d];
    float4 h4 = *(const float4*)&H[(size_t)s * 128 + f4 * 4];
    float* o = AGG + (size_t)d * 128 + f4 * 4;
    atomicAdd(o + 0, h4.x * nrm);
    atomicAdd(o + 1, h4.y * nrm);
    atomicAdd(o + 2, h4.z * nrm);
    atomicAdd(o + 3, h4.w * nrm);
}

// ---------------- Self-loop + bias + ReLU, fused BN statistics ----------------
// Y (in: agg, out: relu(agg + h*dinv^2 + b)), accumulates per-column sum / sumsq.

__global__ __launch_bounds__(256) void selfloop_bn(float* __restrict__ Y,
                                                   const float* __restrict__ H,
                                                   const float* __restrict__ dinv,
                                                   const float* __restrict__ bias,
                                                   float* __restrict__ bnsum,
                                                   float* __restrict__ bnss, int N) {
    int d = threadIdx.x & 127;
    int half = threadIdx.x >> 7;
    float b = bias[d];
    float s = 0.f, ss = 0.f;
    for (int row = blockIdx.x * 2 + half; row < N; row += gridDim.x * 2) {
        float di = dinv[row];
        float v = Y[(size_t)row * 128 + d] + H[(size_t)row * 128 + d] * di * di + b;
        v = fmaxf(v, 0.f);
        Y[(size_t)row * 128 + d] = v;
        s += v; ss += v * v;
    }
    __shared__ float red[256];
    red[threadIdx.x] = s;
    __syncthreads();
    if (threadIdx.x < 128) atomicAdd(&bnsum[d], red[d] + red[d + 128]);
    __syncthreads();
    red[threadIdx.x] = ss;
    __syncthreads();
    if (threadIdx.x < 128) atomicAdd(&bnss[d], red[d] + red[d + 128]);
}

__global__ void bnfinalize(const float* __restrict__ bnsum, const float* __restrict__ bnss,
                           const float* __restrict__ gamma, const float* __restrict__ beta,
                           float* __restrict__ scale, float* __restrict__ shift, float invN) {
    int d = threadIdx.x;   // 128 threads
    float mu  = bnsum[d] * invN;
    float var = bnss[d] * invN - mu * mu;
    float sc  = gamma[d] * rsqrtf(var + 1e-5f);
    scale[d] = sc;
    shift[d] = beta[d] - mu * sc;
}

__global__ __launch_bounds__(256) void bnapply(float* __restrict__ Y,
                                               const float* __restrict__ scale,
                                               const float* __restrict__ shift, int N) {
    int idx = blockIdx.x * 256 + threadIdx.x;
    if (idx >= N * 32) return;
    int d4 = idx & 31;
    float4 sc = ((const float4*)scale)[d4];
    float4 sh = ((const float4*)shift)[d4];
    float4 v = ((float4*)Y)[idx];
    v.x = v.x * sc.x + sh.x;
    v.y = v.y * sc.y + sh.y;
    v.z = v.z * sc.z + sh.z;
    v.w = v.w * sc.w + sh.w;
    ((float4*)Y)[idx] = v;
}

// ---------------- Head: 10 logits per row + log_softmax (wave per row) ----------------

__global__ __launch_bounds__(64) void head_ls(const float* __restrict__ H,
                                              const float* __restrict__ W2t,  // [10][128]
                                              const float* __restrict__ b2,
                                              float* __restrict__ OUT, int N) {
    int row = blockIdx.x;
    int lane = threadIdx.x;
    float2 h = *(const float2*)&H[(size_t)row * 128 + lane * 2];
    float logit[10];
    #pragma unroll
    for (int c = 0; c < 10; ++c) {
        float2 w = *(const float2*)&W2t[c * 128 + lane * 2];
        float p = h.x * w.x + h.y * w.y;
        #pragma unroll
        for (int off = 32; off > 0; off >>= 1) p += __shfl_xor(p, off, 64);
        logit[c] = p + b2[c];
    }
    float m = logit[0];
    #pragma unroll
    for (int c = 1; c < 10; ++c) m = fmaxf(m, logit[c]);
    float sum = 0.f;
    #pragma unroll
    for (int c = 0; c < 10; ++c) sum += expf(logit[c] - m);
    float lse = m + logf(sum);
    if (lane < 10) OUT[(size_t)row * 10 + lane] = logit[lane] - lse;
}

// ---------------- Launch ----------------

extern "C" void kernel_launch(void* const* d_in, const int* in_sizes, int n_in,
                              void* d_out, int out_size, void* d_ws, size_t ws_size,
                              hipStream_t stream) {
    const float* x    = (const float*)d_in[0];
    const int*   ei   = (const int*)d_in[1];
    const float* W1   = (const float*)d_in[2];
    const float* b1   = (const float*)d_in[3];
    const float* g1   = (const float*)d_in[4];
    const float* be1  = (const float*)d_in[5];
    const float* W2   = (const float*)d_in[6];
    const float* b2   = (const float*)d_in[7];
    const float* g2   = (const float*)d_in[8];
    const float* be2  = (const float*)d_in[9];
    const float* l1w  = (const float*)d_in[10];
    const float* l1b  = (const float*)d_in[11];
    const float* l2w  = (const float*)d_in[12];
    const float* l2b  = (const float*)d_in[13];
    float* out = (float*)d_out;

    int N = in_sizes[0] / 128;   // 50000
    int E = in_sizes[1] / 2;     // 640000
    const int* srcp = ei;
    const int* dstp = ei + E;

    float* bufA  = (float*)d_ws;                 // [N][128] linear output h
    float* bufB  = bufA + (size_t)N * 128;       // [N][128] agg / layer output
    float* dinv  = bufB + (size_t)N * 128;       // [N]
    float* bnsum = dinv + N;                     // [128]
    float* bnss  = bnsum + 128;                  // [128]
    float* scale = bnss + 128;                   // [128]
    float* shift = scale + 128;                  // [128]
    float* w2t   = shift + 128;                  // [10][128]

    size_t nd_bytes = (size_t)N * 128 * sizeof(float);
    int gemm_grid = (N + 7) / 8;
    int sc_grid   = (int)(((long long)E * 32 + 255) / 256);

    // degree -> dinv (shared by both layers)
    hipMemsetAsync(dinv, 0, N * sizeof(float), stream);
    deg_count<<<(E + 255) / 256, 256, 0, stream>>>(dstp, dinv, E);
    deg_inv<<<(N + 255) / 256, 256, 0, stream>>>(dinv, N);
    transpose_w2<<<1, 256, 0, stream>>>(l2w, w2t);

    // ---- layer 1 ----
    gemm128<false, false><<<gemm_grid, 256, 0, stream>>>(x, W1, nullptr, bufA, N);
    hipMemsetAsync(bufB, 0, nd_bytes, stream);
    scatter_edges<<<sc_grid, 256, 0, stream>>>(bufA, srcp, dstp, dinv, bufB, E);
    hipMemsetAsync(bnsum, 0, 256 * sizeof(float), stream);
    selfloop_bn<<<1024, 256, 0, stream>>>(bufB, bufA, dinv, b1, bnsum, bnss, N);
    bnfinalize<<<1, 128, 0, stream>>>(bnsum, bnss, g1, be1, scale, shift, 1.0f / N);
    bnapply<<<(N * 32 + 255) / 256, 256, 0, stream>>>(bufB, scale, shift, N);

    // ---- layer 2 ----
    gemm128<false, false><<<gemm_grid, 256, 0, stream>>>(bufB, W2, nullptr, bufA, N);
    hipMemsetAsync(bufB, 0, nd_bytes, stream);
    scatter_edges<<<sc_grid, 256, 0, stream>>>(bufA, srcp, dstp, dinv, bufB, E);
    hipMemsetAsync(bnsum, 0, 256 * sizeof(float), stream);
    selfloop_bn<<<1024, 256, 0, stream>>>(bufB, bufA, dinv, b2, bnsum, bnss, N);
    bnfinalize<<<1, 128, 0, stream>>>(bnsum, bnss, g2, be2, scale, shift, 1.0f / N);
    bnapply<<<(N * 32 + 255) / 256, 256, 0, stream>>>(bufB, scale, shift, N);

    // ---- head ----
    gemm128<true, true><<<gemm_grid, 256, 0, stream>>>(bufB, l1w, l1b, bufA, N);
    head_ls<<<N, 64, 0, stream>>>(bufA, w2t, l2b, out, N);
}

// Round 2
// 749.602 us; speedup vs baseline: 3.4520x; 3.4520x over previous
//
#include <hip/hip_runtime.h>
#include <hip/hip_bf16.h>
#include <math.h>

// ---------------- Degree / normalization ----------------

__global__ void deg_count(const int* __restrict__ dst, int* __restrict__ deg, int E) {
    int e = blockIdx.x * 256 + threadIdx.x;
    if (e < E) atomicAdd(&deg[dst[e]], 1);
}

__global__ void deg_inv(const int* __restrict__ deg, float* __restrict__ dinv, int N) {
    int n = blockIdx.x * 256 + threadIdx.x;
    if (n < N) dinv[n] = rsqrtf((float)deg[n] + 1.0f);   // +1 self-loop
}

// Single-block exclusive scan over deg -> row_start[N+1]
__global__ __launch_bounds__(1024) void scan_rowstart(const int* __restrict__ deg,
                                                      int* __restrict__ row_start, int N) {
    __shared__ int partial[1024];
    int tid = threadIdx.x;
    int chunk = (N + 1023) / 1024;
    int begin = tid * chunk;
    int end = begin + chunk; if (end > N) end = N; if (begin > N) begin = N;
    int s = 0;
    for (int i = begin; i < end; ++i) s += deg[i];
    partial[tid] = s;
    __syncthreads();
    for (int off = 1; off < 1024; off <<= 1) {
        int v = (tid >= off) ? partial[tid - off] : 0;
        __syncthreads();
        partial[tid] += v;
        __syncthreads();
    }
    int excl = (tid == 0) ? 0 : partial[tid - 1];
    for (int i = begin; i < end; ++i) {
        row_start[i] = excl;
        excl += deg[i];
    }
    if (tid == 1023) row_start[N] = excl;   // = E
}

__global__ void copy_cursor(const int* __restrict__ row_start, int* __restrict__ cursor, int N) {
    int n = blockIdx.x * 256 + threadIdx.x;
    if (n < N) cursor[n] = row_start[n];
}

__global__ void csr_fill(const int* __restrict__ src, const int* __restrict__ dst,
                         const float* __restrict__ dinv, int* __restrict__ cursor,
                         int* __restrict__ csr_src, float* __restrict__ csr_nrm, int E) {
    int e = blockIdx.x * 256 + threadIdx.x;
    if (e >= E) return;
    int s = src[e], d = dst[e];
    int pos = atomicAdd(&cursor[d], 1);
    csr_src[pos] = s;
    csr_nrm[pos] = dinv[s] * dinv[d];
}

// ---------------- Tiny transpose of lin2_w [128][10] -> [10][128] ----------------

__global__ void transpose_w2(const float* __restrict__ W, float* __restrict__ Wt) {
    for (int i = threadIdx.x; i < 1280; i += blockDim.x) {
        int k = i / 10, c = i % 10;
        Wt[c * 128 + k] = W[i];
    }
}

// ---------------- GEMM: Y = (AFF ? X*scale+shift : X) @ W (+bias, relu) ----------------

template<bool AFF, bool BIAS, bool RELU>
__global__ __launch_bounds__(256) void gemm128(const float* __restrict__ X,
                                               const float* __restrict__ scale,
                                               const float* __restrict__ shift,
                                               const float* __restrict__ W,
                                               const float* __restrict__ bias,
                                               float* __restrict__ Y, int N) {
    __shared__ float Wl[128 * 128];      // 64 KB
    __shared__ float Xl[8][132];         // +4 pad

    int tid = threadIdx.x;
    {
        const float4* Wg = (const float4*)W;
        float4* Wl4 = (float4*)Wl;
        #pragma unroll
        for (int i = 0; i < 16; ++i) Wl4[tid + i * 256] = Wg[tid + i * 256];
    }
    int n0 = blockIdx.x * 8;
    {
        int r = tid >> 5, k4 = tid & 31;
        if (n0 + r < N) {
            float4 v = *(const float4*)&X[(size_t)(n0 + r) * 128 + k4 * 4];
            if (AFF) {
                float4 sc = ((const float4*)scale)[k4];
                float4 sh = ((const float4*)shift)[k4];
                v.x = v.x * sc.x + sh.x; v.y = v.y * sc.y + sh.y;
                v.z = v.z * sc.z + sh.z; v.w = v.w * sc.w + sh.w;
            }
            *(float4*)&Xl[r][k4 * 4] = v;
        }
    }
    __syncthreads();

    int r = tid >> 5, c4 = tid & 31;
    float4 acc = {0.f, 0.f, 0.f, 0.f};
    const float4* Wrow = (const float4*)Wl;
    #pragma unroll 8
    for (int k = 0; k < 128; ++k) {
        float xv = Xl[r][k];
        float4 w = Wrow[k * 32 + c4];
        acc.x += xv * w.x; acc.y += xv * w.y; acc.z += xv * w.z; acc.w += xv * w.w;
    }
    if (n0 + r < N) {
        if (BIAS) {
            float4 b = ((const float4*)bias)[c4];
            acc.x += b.x; acc.y += b.y; acc.z += b.z; acc.w += b.w;
        }
        if (RELU) {
            acc.x = fmaxf(acc.x, 0.f); acc.y = fmaxf(acc.y, 0.f);
            acc.z = fmaxf(acc.z, 0.f); acc.w = fmaxf(acc.w, 0.f);
        }
        ((float4*)Y)[(size_t)(n0 + r) * 32 + c4] = acc;
    }
}

// ---------------- Gather aggregation, fused self-loop+bias+ReLU+BN-stats ----------------
// One wave (64 lanes) per node; lane owns feature columns {2*lane, 2*lane+1}.

__global__ __launch_bounds__(256) void gather_fused(const float* __restrict__ H,
                                                    const int* __restrict__ row_start,
                                                    const int* __restrict__ csr_src,
                                                    const float* __restrict__ csr_nrm,
                                                    const float* __restrict__ dinv,
                                                    const float* __restrict__ bias,
                                                    float* __restrict__ Y,
                                                    float* __restrict__ bnsum,
                                                    float* __restrict__ bnss, int N) {
    int g = threadIdx.x >> 6;        // wave id in block (0..3)
    int lane = threadIdx.x & 63;
    int d = lane * 2;
    float b0 = bias[d], b1 = bias[d + 1];
    float s0 = 0.f, ss0 = 0.f, s1 = 0.f, ss1 = 0.f;

    for (int n = blockIdx.x * 4 + g; n < N; n += gridDim.x * 4) {
        int e0 = row_start[n], e1 = row_start[n + 1];
        float a0 = 0.f, a1 = 0.f;
        for (int e = e0; e < e1; ++e) {
            int s = csr_src[e];
            float nrm = csr_nrm[e];
            float2 h = *(const float2*)&H[(size_t)s * 128 + d];
            a0 += h.x * nrm;
            a1 += h.y * nrm;
        }
        float di = dinv[n], dii = di * di;
        float2 hn = *(const float2*)&H[(size_t)n * 128 + d];
        a0 = fmaxf(a0 + hn.x * dii + b0, 0.f);
        a1 = fmaxf(a1 + hn.y * dii + b1, 0.f);
        *(float2*)&Y[(size_t)n * 128 + d] = make_float2(a0, a1);
        s0 += a0; ss0 += a0 * a0;
        s1 += a1; ss1 += a1 * a1;
    }

    // reduce the 4 waves' partials, one atomic per column per stat per block
    __shared__ float red[256];
    red[threadIdx.x] = s0; __syncthreads();
    if (g == 0) atomicAdd(&bnsum[d],     red[lane] + red[64 + lane] + red[128 + lane] + red[192 + lane]);
    __syncthreads();
    red[threadIdx.x] = s1; __syncthreads();
    if (g == 0) atomicAdd(&bnsum[d + 1], red[lane] + red[64 + lane] + red[128 + lane] + red[192 + lane]);
    __syncthreads();
    red[threadIdx.x] = ss0; __syncthreads();
    if (g == 0) atomicAdd(&bnss[d],      red[lane] + red[64 + lane] + red[128 + lane] + red[192 + lane]);
    __syncthreads();
    red[threadIdx.x] = ss1; __syncthreads();
    if (g == 0) atomicAdd(&bnss[d + 1],  red[lane] + red[64 + lane] + red[128 + lane] + red[192 + lane]);
}

__global__ void bnfinalize(const float* __restrict__ bnsum, const float* __restrict__ bnss,
                           const float* __restrict__ gamma, const float* __restrict__ beta,
                           float* __restrict__ scale, float* __restrict__ shift, float invN) {
    int d = threadIdx.x;   // 128 threads
    float mu  = bnsum[d] * invN;
    float var = bnss[d] * invN - mu * mu;
    float sc  = gamma[d] * rsqrtf(var + 1e-5f);
    scale[d] = sc;
    shift[d] = beta[d] - mu * sc;
}

// ---------------- Head: 10 logits per row + log_softmax (wave per row) ----------------

__global__ __launch_bounds__(64) void head_ls(const float* __restrict__ H,
                                              const float* __restrict__ W2t,  // [10][128]
                                              const float* __restrict__ b2,
                                              float* __restrict__ OUT, int N) {
    int row = blockIdx.x;
    int lane = threadIdx.x;
    float2 h = *(const float2*)&H[(size_t)row * 128 + lane * 2];
    float logit[10];
    #pragma unroll
    for (int c = 0; c < 10; ++c) {
        float2 w = *(const float2*)&W2t[c * 128 + lane * 2];
        float p = h.x * w.x + h.y * w.y;
        #pragma unroll
        for (int off = 32; off > 0; off >>= 1) p += __shfl_xor(p, off, 64);
        logit[c] = p + b2[c];
    }
    float m = logit[0];
    #pragma unroll
    for (int c = 1; c < 10; ++c) m = fmaxf(m, logit[c]);
    float sum = 0.f;
    #pragma unroll
    for (int c = 0; c < 10; ++c) sum += expf(logit[c] - m);
    float lse = m + logf(sum);
    if (lane < 10) OUT[(size_t)row * 10 + lane] = logit[lane] - lse;
}

// ---------------- Launch ----------------

extern "C" void kernel_launch(void* const* d_in, const int* in_sizes, int n_in,
                              void* d_out, int out_size, void* d_ws, size_t ws_size,
                              hipStream_t stream) {
    const float* x    = (const float*)d_in[0];
    const int*   ei   = (const int*)d_in[1];
    const float* W1   = (const float*)d_in[2];
    const float* b1   = (const float*)d_in[3];
    const float* g1   = (const float*)d_in[4];
    const float* be1  = (const float*)d_in[5];
    const float* W2   = (const float*)d_in[6];
    const float* b2   = (const float*)d_in[7];
    const float* g2   = (const float*)d_in[8];
    const float* be2  = (const float*)d_in[9];
    const float* l1w  = (const float*)d_in[10];
    const float* l1b  = (const float*)d_in[11];
    const float* l2w  = (const float*)d_in[12];
    const float* l2b  = (const float*)d_in[13];
    float* out = (float*)d_out;

    int N = in_sizes[0] / 128;   // 50000
    int E = in_sizes[1] / 2;     // 640000
    const int* srcp = ei;
    const int* dstp = ei + E;

    char* w = (char*)d_ws;
    float* bufA     = (float*)w;                    w += (size_t)N * 128 * 4;
    float* bufB     = (float*)w;                    w += (size_t)N * 128 * 4;
    float* dinv     = (float*)w;                    w += (size_t)N * 4;
    int*   degc     = (int*)w;                      w += (size_t)N * 4;
    int*   row_st   = (int*)w;                      w += (size_t)(N + 1) * 4;
    int*   cursor   = (int*)w;                      w += (size_t)N * 4;
    int*   csr_src  = (int*)w;                      w += (size_t)E * 4;
    float* csr_nrm  = (float*)w;                    w += (size_t)E * 4;
    float* bnsum    = (float*)w;                    w += 128 * 4;
    float* bnss     = (float*)w;                    w += 128 * 4;
    float* scale    = (float*)w;                    w += 128 * 4;
    float* shift    = (float*)w;                    w += 128 * 4;
    float* w2t      = (float*)w;                    w += 1280 * 4;

    int gemm_grid = (N + 7) / 8;
    int eg = (E + 255) / 256, ng = (N + 255) / 256;

    // ---- CSR build (shared by both layers) ----
    hipMemsetAsync(degc, 0, (size_t)N * 4, stream);
    deg_count<<<eg, 256, 0, stream>>>(dstp, degc, E);
    deg_inv<<<ng, 256, 0, stream>>>(degc, dinv, N);
    scan_rowstart<<<1, 1024, 0, stream>>>(degc, row_st, N);
    copy_cursor<<<ng, 256, 0, stream>>>(row_st, cursor, N);
    csr_fill<<<eg, 256, 0, stream>>>(srcp, dstp, dinv, cursor, csr_src, csr_nrm, E);
    transpose_w2<<<1, 256, 0, stream>>>(l2w, w2t);

    // ---- layer 1 ----
    gemm128<false, false, false><<<gemm_grid, 256, 0, stream>>>(x, nullptr, nullptr, W1, nullptr, bufA, N);
    hipMemsetAsync(bnsum, 0, 256 * 4, stream);   // bnsum + bnss
    gather_fused<<<1024, 256, 0, stream>>>(bufA, row_st, csr_src, csr_nrm, dinv, b1, bufB, bnsum, bnss, N);
    bnfinalize<<<1, 128, 0, stream>>>(bnsum, bnss, g1, be1, scale, shift, 1.0f / N);

    // ---- layer 2 ----
    gemm128<true, false, false><<<gemm_grid, 256, 0, stream>>>(bufB, scale, shift, W2, nullptr, bufA, N);
    hipMemsetAsync(bnsum, 0, 256 * 4, stream);
    gather_fused<<<1024, 256, 0, stream>>>(bufA, row_st, csr_src, csr_nrm, dinv, b2, bufB, bnsum, bnss, N);
    bnfinalize<<<1, 128, 0, stream>>>(bnsum, bnss, g2, be2, scale, shift, 1.0f / N);

    // ---- head ----
    gemm128<true, true, true><<<gemm_grid, 256, 0, stream>>>(bufB, scale, shift, l1w, l1b, bufA, N);
    head_ls<<<N, 64, 0, stream>>>(bufA, w2t, l2b, out, N);
}

// Round 3
// 626.267 us; speedup vs baseline: 4.1318x; 1.1969x over previous
//
#include <hip/hip_runtime.h>
#include <hip/hip_bf16.h>
#include <math.h>

typedef unsigned int uint;
typedef unsigned short ushort;
using f32x4 = __attribute__((ext_vector_type(4))) float;
using s16x8 = __attribute__((ext_vector_type(8))) short;

__device__ __forceinline__ float bflo(uint u) { return __uint_as_float(u << 16); }
__device__ __forceinline__ float bfhi(uint u) { return __uint_as_float(u & 0xffff0000u); }
__device__ __forceinline__ ushort f2bf(float f) {
    uint u = __float_as_uint(f);
    return (ushort)((u + 0x7fffu + ((u >> 16) & 1u)) >> 16);   // RNE
}

// ---------------- Degree / normalization / CSR ----------------

__global__ void deg_count(const int* __restrict__ dst, int* __restrict__ deg, int E) {
    int e = blockIdx.x * 256 + threadIdx.x;
    if (e < E) atomicAdd(&deg[dst[e]], 1);
}

__global__ void deg_inv(const int* __restrict__ deg, float* __restrict__ dinv, int N) {
    int n = blockIdx.x * 256 + threadIdx.x;
    if (n < N) dinv[n] = rsqrtf((float)deg[n] + 1.0f);   // +1 self-loop
}

__global__ __launch_bounds__(1024) void scan_rowstart(const int* __restrict__ deg,
                                                      int* __restrict__ row_start, int N) {
    __shared__ int partial[1024];
    int tid = threadIdx.x;
    int chunk = (N + 1023) / 1024;
    int begin = tid * chunk;
    int end = begin + chunk; if (end > N) end = N; if (begin > N) begin = N;
    int s = 0;
    for (int i = begin; i < end; ++i) s += deg[i];
    partial[tid] = s;
    __syncthreads();
    for (int off = 1; off < 1024; off <<= 1) {
        int v = (tid >= off) ? partial[tid - off] : 0;
        __syncthreads();
        partial[tid] += v;
        __syncthreads();
    }
    int excl = (tid == 0) ? 0 : partial[tid - 1];
    for (int i = begin; i < end; ++i) {
        row_start[i] = excl;
        excl += deg[i];
    }
    if (tid == 1023) row_start[N] = excl;   // = E
}

__global__ void copy_cursor(const int* __restrict__ row_start, int* __restrict__ cursor, int N) {
    int n = blockIdx.x * 256 + threadIdx.x;
    if (n < N) cursor[n] = row_start[n];
}

__global__ void csr_fill(const int* __restrict__ src, const int* __restrict__ dst,
                         const float* __restrict__ dinv, int* __restrict__ cursor,
                         int2* __restrict__ csr2, int E) {
    int e = blockIdx.x * 256 + threadIdx.x;
    if (e >= E) return;
    int s = src[e], d = dst[e];
    int pos = atomicAdd(&cursor[d], 1);
    csr2[pos] = make_int2(s, __float_as_int(dinv[s] * dinv[d]));
}

// ---------------- Weight prep ----------------

// W [128 k][128 n] f32 -> Wt [128 n][128 k] bf16
__global__ void convert_wT(const float* __restrict__ W, ushort* __restrict__ Wt) {
    int i = blockIdx.x * 256 + threadIdx.x;      // 16384 elements
    int k = i >> 7, n = i & 127;
    Wt[n * 128 + k] = f2bf(W[i]);
}

__global__ void transpose_w2(const float* __restrict__ W, float* __restrict__ Wt) {
    for (int i = threadIdx.x; i < 1280; i += blockDim.x) {
        int k = i / 10, c = i % 10;
        Wt[c * 128 + k] = W[i];
    }
}

// ---------------- bf16 MFMA GEMM: Y = f(X') @ W, X' = affine(X) optionally ----------------
// M=N rows, K=128, N=128. Block: 256 thr (4 waves), 64 rows. LDS A 16KB + B^T 32KB, XOR-swizzled.

template<bool XF32, bool AFF, bool BIAS, bool RELU>
__global__ __launch_bounds__(256) void gemm_mfma(const void* __restrict__ Xv,
                                                 const float* __restrict__ scale,
                                                 const float* __restrict__ shift,
                                                 const ushort* __restrict__ Bt,
                                                 const float* __restrict__ bias,
                                                 ushort* __restrict__ Y, int N) {
    __shared__ char smem[16384 + 32768];
    char* Al = smem;            // 64 rows x 256B, unit u at row*256 + (u^(row&7))*16
    char* Bl = smem + 16384;    // 128 n-rows x 256B, same swizzle

    int tid = threadIdx.x;
    int brow = blockIdx.x * 64;

    // stage B^T (bf16, pre-transposed): thread t covers n = t>>1, half = t&1
    {
        int n = tid >> 1, h = tid & 1;
        const uint4* srcp = (const uint4*)(Bt + n * 128 + h * 64);
        #pragma unroll
        for (int i = 0; i < 8; ++i) {
            uint4 v = srcp[i];
            int u = (h * 8 + i) ^ (n & 7);
            *(uint4*)(Bl + n * 256 + u * 16) = v;
        }
    }
    // stage A: thread t covers row r = t>>2, cols (t&3)*32..+31
    {
        int r = tid >> 2, c0 = (tid & 3) * 32;
        int row = brow + r;
        bool ok = row < N;
        uint pk[16];
        if (XF32) {
            const float* Xr = (const float*)Xv + (size_t)row * 128 + c0;
            #pragma unroll
            for (int i = 0; i < 16; ++i) {
                float f0 = ok ? Xr[i * 2] : 0.f;
                float f1 = ok ? Xr[i * 2 + 1] : 0.f;
                pk[i] = (uint)f2bf(f0) | ((uint)f2bf(f1) << 16);
            }
        } else {
            const uint* Xr = (const uint*)((const ushort*)Xv + (size_t)row * 128 + c0);
            #pragma unroll
            for (int i = 0; i < 16; ++i) {
                uint u = ok ? Xr[i] : 0u;
                float f0 = bflo(u), f1 = bfhi(u);
                if (AFF) {
                    int c = c0 + i * 2;
                    f0 = f0 * scale[c] + shift[c];
                    f1 = f1 * scale[c + 1] + shift[c + 1];
                }
                pk[i] = (uint)f2bf(f0) | ((uint)f2bf(f1) << 16);
            }
        }
        #pragma unroll
        for (int i = 0; i < 4; ++i) {
            int u = ((tid & 3) * 4 + i) ^ (r & 7);
            *(uint4*)(Al + r * 256 + u * 16) = *(uint4*)&pk[i * 4];
        }
    }
    __syncthreads();

    int lane = tid & 63, w = tid >> 6;
    int m = lane & 15, g = lane >> 4;
    int wr = w * 16;

    f32x4 acc[8];
    #pragma unroll
    for (int nt = 0; nt < 8; ++nt) acc[nt] = (f32x4){0.f, 0.f, 0.f, 0.f};

    #pragma unroll
    for (int kk = 0; kk < 4; ++kk) {
        int u = (kk * 4 + g) ^ (m & 7);
        s16x8 a = *(const s16x8*)(Al + (wr + m) * 256 + u * 16);
        #pragma unroll
        for (int nt = 0; nt < 8; ++nt) {
            s16x8 b = *(const s16x8*)(Bl + (nt * 16 + m) * 256 + u * 16);
            acc[nt] = __builtin_amdgcn_mfma_f32_16x16x32_bf16(a, b, acc[nt], 0, 0, 0);
        }
    }

    float bv[8];
    if (BIAS) {
        #pragma unroll
        for (int nt = 0; nt < 8; ++nt) bv[nt] = bias[nt * 16 + m];
    }
    #pragma unroll
    for (int i = 0; i < 4; ++i) {
        int row = brow + wr + g * 4 + i;
        if (row < N) {
            #pragma unroll
            for (int nt = 0; nt < 8; ++nt) {
                float v = acc[nt][i];
                if (BIAS) v += bv[nt];
                if (RELU) v = fmaxf(v, 0.f);
                Y[(size_t)row * 128 + nt * 16 + m] = f2bf(v);
            }
        }
    }
}

// ---------------- Gather aggregation (bf16 H), fused self-loop+bias+ReLU+BN-stats ----------------
// One wave per node; lane owns cols {2l,2l+1}. Edge meta shfl-broadcast, 4x unrolled gathers.

__global__ __launch_bounds__(256) void gather_fused(const ushort* __restrict__ H,
                                                    const int* __restrict__ row_start,
                                                    const int2* __restrict__ csr2,
                                                    const float* __restrict__ dinv,
                                                    const float* __restrict__ bias,
                                                    ushort* __restrict__ Y,
                                                    float* __restrict__ bnsum,
                                                    float* __restrict__ bnss, int N) {
    int g = threadIdx.x >> 6, lane = threadIdx.x & 63;
    int d = lane * 2;
    float b0 = bias[d], b1 = bias[d + 1];
    float s0 = 0.f, s1 = 0.f, ss0 = 0.f, ss1 = 0.f;
    int stride = gridDim.x * 4;

    for (int n = blockIdx.x * 4 + g; n < N; n += stride) {
        int e0 = row_start[n], e1 = row_start[n + 1];
        float a0 = 0.f, a1 = 0.f;
        for (int base = e0; base < e1; base += 64) {
            int cnt = min(64, e1 - base);
            int2 me = (lane < cnt) ? csr2[base + lane] : make_int2(0, 0);
            int sl = me.x;
            float nl = __int_as_float(me.y);
            int j = 0;
            for (; j + 4 <= cnt; j += 4) {
                int   sA = __shfl(sl, j + 0); float nA = __shfl(nl, j + 0);
                int   sB = __shfl(sl, j + 1); float nB = __shfl(nl, j + 1);
                int   sC = __shfl(sl, j + 2); float nC = __shfl(nl, j + 2);
                int   sD = __shfl(sl, j + 3); float nD = __shfl(nl, j + 3);
                uint vA = *(const uint*)&H[(size_t)sA * 128 + d];
                uint vB = *(const uint*)&H[(size_t)sB * 128 + d];
                uint vC = *(const uint*)&H[(size_t)sC * 128 + d];
                uint vD = *(const uint*)&H[(size_t)sD * 128 + d];
                a0 += bflo(vA) * nA + bflo(vB) * nB + bflo(vC) * nC + bflo(vD) * nD;
                a1 += bfhi(vA) * nA + bfhi(vB) * nB + bfhi(vC) * nC + bfhi(vD) * nD;
            }
            for (; j < cnt; ++j) {
                int s = __shfl(sl, j);
                float nm = __shfl(nl, j);
                uint v = *(const uint*)&H[(size_t)s * 128 + d];
                a0 += bflo(v) * nm;
                a1 += bfhi(v) * nm;
            }
        }
        float di = dinv[n], dii = di * di;
        uint hv = *(const uint*)&H[(size_t)n * 128 + d];
        a0 = fmaxf(a0 + bflo(hv) * dii + b0, 0.f);
        a1 = fmaxf(a1 + bfhi(hv) * dii + b1, 0.f);
        *(uint*)&Y[(size_t)n * 128 + d] = (uint)f2bf(a0) | ((uint)f2bf(a1) << 16);
        s0 += a0; ss0 += a0 * a0;
        s1 += a1; ss1 += a1 * a1;
    }

    __shared__ float red[4][128];
    red[g][d] = s0; red[g][d + 1] = s1;
    __syncthreads();
    if (g == 0) {
        atomicAdd(&bnsum[d],     red[0][d] + red[1][d] + red[2][d] + red[3][d]);
        atomicAdd(&bnsum[d + 1], red[0][d + 1] + red[1][d + 1] + red[2][d + 1] + red[3][d + 1]);
    }
    __syncthreads();
    red[g][d] = ss0; red[g][d + 1] = ss1;
    __syncthreads();
    if (g == 0) {
        atomicAdd(&bnss[d],     red[0][d] + red[1][d] + red[2][d] + red[3][d]);
        atomicAdd(&bnss[d + 1], red[0][d + 1] + red[1][d + 1] + red[2][d + 1] + red[3][d + 1]);
    }
}

__global__ void bnfinalize(const float* __restrict__ bnsum, const float* __restrict__ bnss,
                           const float* __restrict__ gamma, const float* __restrict__ beta,
                           float* __restrict__ scale, float* __restrict__ shift, float invN) {
    int d = threadIdx.x;   // 128 threads
    float mu  = bnsum[d] * invN;
    float var = bnss[d] * invN - mu * mu;
    float sc  = gamma[d] * rsqrtf(var + 1e-5f);
    scale[d] = sc;
    shift[d] = beta[d] - mu * sc;
}

// ---------------- Head: 10 logits + log_softmax (wave per row, 4 rows/block) ----------------

__global__ __launch_bounds__(256) void head_ls(const ushort* __restrict__ H,
                                               const float* __restrict__ W2t,  // [10][128]
                                               const float* __restrict__ b2,
                                               float* __restrict__ OUT, int N) {
    int wv = threadIdx.x >> 6, lane = threadIdx.x & 63;
    int row = blockIdx.x * 4 + wv;
    if (row >= N) return;
    uint hv = *(const uint*)&H[(size_t)row * 128 + lane * 2];
    float h0 = bflo(hv), h1 = bfhi(hv);
    float logit[10];
    #pragma unroll
    for (int c = 0; c < 10; ++c) {
        float2 w = *(const float2*)&W2t[c * 128 + lane * 2];
        float p = h0 * w.x + h1 * w.y;
        #pragma unroll
        for (int off = 32; off > 0; off >>= 1) p += __shfl_xor(p, off, 64);
        logit[c] = p + b2[c];
    }
    float m = logit[0];
    #pragma unroll
    for (int c = 1; c < 10; ++c) m = fmaxf(m, logit[c]);
    float sum = 0.f;
    #pragma unroll
    for (int c = 0; c < 10; ++c) sum += expf(logit[c] - m);
    float lse = m + logf(sum);
    if (lane < 10) OUT[(size_t)row * 10 + lane] = logit[lane] - lse;
}

// ---------------- Launch ----------------

static inline char* align16(char* p) { return (char*)(((uintptr_t)p + 15) & ~(uintptr_t)15); }

extern "C" void kernel_launch(void* const* d_in, const int* in_sizes, int n_in,
                              void* d_out, int out_size, void* d_ws, size_t ws_size,
                              hipStream_t stream) {
    const float* x    = (const float*)d_in[0];
    const int*   ei   = (const int*)d_in[1];
    const float* W1   = (const float*)d_in[2];
    const float* b1   = (const float*)d_in[3];
    const float* g1   = (const float*)d_in[4];
    const float* be1  = (const float*)d_in[5];
    const float* W2   = (const float*)d_in[6];
    const float* b2   = (const float*)d_in[7];
    const float* g2   = (const float*)d_in[8];
    const float* be2  = (const float*)d_in[9];
    const float* l1w  = (const float*)d_in[10];
    const float* l1b  = (const float*)d_in[11];
    const float* l2w  = (const float*)d_in[12];
    const float* l2b  = (const float*)d_in[13];
    float* out = (float*)d_out;

    int N = in_sizes[0] / 128;   // 50000
    int E = in_sizes[1] / 2;     // 640000
    const int* srcp = ei;
    const int* dstp = ei + E;

    char* w = (char*)d_ws;
    ushort* bufA  = (ushort*)w;  w = align16(w + (size_t)N * 128 * 2);
    ushort* bufB  = (ushort*)w;  w = align16(w + (size_t)N * 128 * 2);
    float* dinv   = (float*)w;   w = align16(w + (size_t)N * 4);
    int*   degc   = (int*)w;     w = align16(w + (size_t)N * 4);
    int*   row_st = (int*)w;     w = align16(w + (size_t)(N + 1) * 4);
    int*   cursor = (int*)w;     w = align16(w + (size_t)N * 4);
    int2*  csr2   = (int2*)w;    w = align16(w + (size_t)E * 8);
    float* bnsum  = (float*)w;   w = align16(w + 128 * 4);
    float* bnss   = (float*)w;   w = align16(w + 128 * 4);
    float* scale  = (float*)w;   w = align16(w + 128 * 4);
    float* shift  = (float*)w;   w = align16(w + 128 * 4);
    float* w2t    = (float*)w;   w = align16(w + 1280 * 4);
    ushort* wt1   = (ushort*)w;  w = align16(w + 16384 * 2);
    ushort* wt2   = (ushort*)w;  w = align16(w + 16384 * 2);
    ushort* wt3   = (ushort*)w;  w = align16(w + 16384 * 2);

    int eg = (E + 255) / 256, ng = (N + 255) / 256;
    int gemm_grid = (N + 63) / 64;
    int gather_grid = 1536;

    // ---- CSR build + weight prep ----
    hipMemsetAsync(degc, 0, (size_t)N * 4, stream);
    deg_count<<<eg, 256, 0, stream>>>(dstp, degc, E);
    deg_inv<<<ng, 256, 0, stream>>>(degc, dinv, N);
    scan_rowstart<<<1, 1024, 0, stream>>>(degc, row_st, N);
    copy_cursor<<<ng, 256, 0, stream>>>(row_st, cursor, N);
    csr_fill<<<eg, 256, 0, stream>>>(srcp, dstp, dinv, cursor, csr2, E);
    convert_wT<<<64, 256, 0, stream>>>(W1, wt1);
    convert_wT<<<64, 256, 0, stream>>>(W2, wt2);
    convert_wT<<<64, 256, 0, stream>>>(l1w, wt3);
    transpose_w2<<<1, 256, 0, stream>>>(l2w, w2t);

    // ---- layer 1 ----
    gemm_mfma<true, false, false, false><<<gemm_grid, 256, 0, stream>>>(x, nullptr, nullptr, wt1, nullptr, bufA, N);
    hipMemsetAsync(bnsum, 0, 1024, stream);   // bnsum + bnss
    gather_fused<<<gather_grid, 256, 0, stream>>>(bufA, row_st, csr2, dinv, b1, bufB, bnsum, bnss, N);
    bnfinalize<<<1, 128, 0, stream>>>(bnsum, bnss, g1, be1, scale, shift, 1.0f / N);

    // ---- layer 2 ----
    gemm_mfma<false, true, false, false><<<gemm_grid, 256, 0, stream>>>(bufB, scale, shift, wt2, nullptr, bufA, N);
    hipMemsetAsync(bnsum, 0, 1024, stream);
    gather_fused<<<gather_grid, 256, 0, stream>>>(bufA, row_st, csr2, dinv, b2, bufB, bnsum, bnss, N);
    bnfinalize<<<1, 128, 0, stream>>>(bnsum, bnss, g2, be2, scale, shift, 1.0f / N);

    // ---- head ----
    gemm_mfma<false, true, true, true><<<gemm_grid, 256, 0, stream>>>(bufB, scale, shift, wt3, l1b, bufA, N);
    head_ls<<<(N + 3) / 4, 256, 0, stream>>>(bufA, w2t, l2b, out, N);
}

// Round 4
// 575.516 us; speedup vs baseline: 4.4962x; 1.0882x over previous
//
#include <hip/hip_runtime.h>
#include <hip/hip_bf16.h>
#include <math.h>

typedef unsigned int uint;
typedef unsigned short ushort;
using f32x4 = __attribute__((ext_vector_type(4))) float;
using s16x8 = __attribute__((ext_vector_type(8))) short;

__device__ __forceinline__ float bflo(uint u) { return __uint_as_float(u << 16); }
__device__ __forceinline__ float bfhi(uint u) { return __uint_as_float(u & 0xffff0000u); }
__device__ __forceinline__ ushort f2bf(float f) {
    uint u = __float_as_uint(f);
    return (ushort)((u + 0x7fffu + ((u >> 16) & 1u)) >> 16);   // RNE
}
__device__ __forceinline__ float sel4f(float a, float b, float c, float d, int i) {
    float r = a; r = (i == 1) ? b : r; r = (i == 2) ? c : r; r = (i == 3) ? d : r; return r;
}
__device__ __forceinline__ int sel4i(int a, int b, int c, int d, int i) {
    int r = a; r = (i == 1) ? b : r; r = (i == 2) ? c : r; r = (i == 3) ? d : r; return r;
}

// ---------------- Degree / CSR ----------------

__global__ void deg_count(const int* __restrict__ dst, int* __restrict__ deg, int E) {
    int e = blockIdx.x * 256 + threadIdx.x;
    if (e < E) atomicAdd(&deg[dst[e]], 1);
}

// scan -> row_start, cursor copy, dinv — all in one block
__global__ __launch_bounds__(1024) void scan_all(const int* __restrict__ deg,
                                                 int* __restrict__ row_start,
                                                 int* __restrict__ cursor,
                                                 float* __restrict__ dinv, int N) {
    __shared__ int partial[1024];
    int tid = threadIdx.x;
    int chunk = (N + 1023) / 1024;
    int begin = tid * chunk;
    int end = begin + chunk; if (end > N) end = N; if (begin > N) begin = N;
    int s = 0;
    for (int i = begin; i < end; ++i) s += deg[i];
    partial[tid] = s;
    __syncthreads();
    for (int off = 1; off < 1024; off <<= 1) {
        int v = (tid >= off) ? partial[tid - off] : 0;
        __syncthreads();
        partial[tid] += v;
        __syncthreads();
    }
    int excl = (tid == 0) ? 0 : partial[tid - 1];
    for (int i = begin; i < end; ++i) {
        int dg = deg[i];
        row_start[i] = excl;
        cursor[i] = excl;
        dinv[i] = rsqrtf((float)dg + 1.0f);
        excl += dg;
    }
    if (tid == 1023) row_start[N] = excl;   // = E
}

__global__ void csr_fill(const int* __restrict__ src, const int* __restrict__ dst,
                         const float* __restrict__ dinv, int* __restrict__ cursor,
                         int2* __restrict__ csr2, int E) {
    int e = blockIdx.x * 256 + threadIdx.x;
    if (e >= E) return;
    int s = src[e], d = dst[e];
    int pos = atomicAdd(&cursor[d], 1);
    csr2[pos] = make_int2(s, __float_as_int(dinv[s] * dinv[d]));
}

// ---------------- Weight prep: 3x (W [k][n] f32 -> [n][k] bf16) + w2t ----------------

__global__ __launch_bounds__(256) void prep_weights(const float* __restrict__ W1,
                                                    const float* __restrict__ W2,
                                                    const float* __restrict__ W3,
                                                    const float* __restrict__ l2w,
                                                    ushort* __restrict__ wt1,
                                                    ushort* __restrict__ wt2,
                                                    ushort* __restrict__ wt3,
                                                    float* __restrict__ w2t) {
    int i = blockIdx.x * 256 + threadIdx.x;      // 0..49151
    int li = i & 16383;
    int k = li >> 7, n = li & 127;
    const float* Ws = (i < 16384) ? W1 : (i < 32768) ? W2 : W3;
    ushort* Wd = (i < 16384) ? wt1 : (i < 32768) ? wt2 : wt3;
    Wd[n * 128 + k] = f2bf(Ws[li]);
    if (i < 1280) {
        int kk = i / 10, c = i % 10;
        w2t[c * 128 + kk] = l2w[i];
    }
}

// ---------------- bf16 MFMA GEMM ----------------

template<bool XF32, bool AFF, bool BIAS, bool RELU>
__global__ __launch_bounds__(256) void gemm_mfma(const void* __restrict__ Xv,
                                                 const float* __restrict__ scale,
                                                 const float* __restrict__ shift,
                                                 const ushort* __restrict__ Bt,
                                                 const float* __restrict__ bias,
                                                 ushort* __restrict__ Y, int N) {
    __shared__ char smem[16384 + 32768];
    char* Al = smem;            // 64 rows x 256B, unit u at row*256 + (u^(row&7))*16
    char* Bl = smem + 16384;    // 128 n-rows x 256B, same swizzle

    int tid = threadIdx.x;
    int brow = blockIdx.x * 64;

    {
        int n = tid >> 1, h = tid & 1;
        const uint4* srcp = (const uint4*)(Bt + n * 128 + h * 64);
        #pragma unroll
        for (int i = 0; i < 8; ++i) {
            uint4 v = srcp[i];
            int u = (h * 8 + i) ^ (n & 7);
            *(uint4*)(Bl + n * 256 + u * 16) = v;
        }
    }
    {
        int r = tid >> 2, c0 = (tid & 3) * 32;
        int row = brow + r;
        bool ok = row < N;
        uint pk[16];
        if (XF32) {
            const float* Xr = (const float*)Xv + (size_t)row * 128 + c0;
            #pragma unroll
            for (int i = 0; i < 16; ++i) {
                float f0 = ok ? Xr[i * 2] : 0.f;
                float f1 = ok ? Xr[i * 2 + 1] : 0.f;
                pk[i] = (uint)f2bf(f0) | ((uint)f2bf(f1) << 16);
            }
        } else {
            const uint* Xr = (const uint*)((const ushort*)Xv + (size_t)row * 128 + c0);
            #pragma unroll
            for (int i = 0; i < 16; ++i) {
                uint u = ok ? Xr[i] : 0u;
                float f0 = bflo(u), f1 = bfhi(u);
                if (AFF) {
                    int c = c0 + i * 2;
                    f0 = f0 * scale[c] + shift[c];
                    f1 = f1 * scale[c + 1] + shift[c + 1];
                }
                pk[i] = (uint)f2bf(f0) | ((uint)f2bf(f1) << 16);
            }
        }
        #pragma unroll
        for (int i = 0; i < 4; ++i) {
            int u = ((tid & 3) * 4 + i) ^ (r & 7);
            *(uint4*)(Al + r * 256 + u * 16) = *(uint4*)&pk[i * 4];
        }
    }
    __syncthreads();

    int lane = tid & 63, w = tid >> 6;
    int m = lane & 15, g = lane >> 4;
    int wr = w * 16;

    f32x4 acc[8];
    #pragma unroll
    for (int nt = 0; nt < 8; ++nt) acc[nt] = (f32x4){0.f, 0.f, 0.f, 0.f};

    #pragma unroll
    for (int kk = 0; kk < 4; ++kk) {
        int u = (kk * 4 + g) ^ (m & 7);
        s16x8 a = *(const s16x8*)(Al + (wr + m) * 256 + u * 16);
        #pragma unroll
        for (int nt = 0; nt < 8; ++nt) {
            s16x8 b = *(const s16x8*)(Bl + (nt * 16 + m) * 256 + u * 16);
            acc[nt] = __builtin_amdgcn_mfma_f32_16x16x32_bf16(a, b, acc[nt], 0, 0, 0);
        }
    }

    float bv[8];
    if (BIAS) {
        #pragma unroll
        for (int nt = 0; nt < 8; ++nt) bv[nt] = bias[nt * 16 + m];
    }
    #pragma unroll
    for (int i = 0; i < 4; ++i) {
        int row = brow + wr + g * 4 + i;
        if (row < N) {
            #pragma unroll
            for (int nt = 0; nt < 8; ++nt) {
                float v = acc[nt][i];
                if (BIAS) v += bv[nt];
                if (RELU) v = fmaxf(v, 0.f);
                Y[(size_t)row * 128 + nt * 16 + m] = f2bf(v);
            }
        }
    }
}

// ---------------- Chunked segmented gather + self-loop + bias + ReLU + BN stats ----------------
// Wave owns 4 consecutive nodes (contiguous CSR edges). 8-deep load pipeline.

__global__ __launch_bounds__(256) void gather_fused(const ushort* __restrict__ H,
                                                    const int* __restrict__ row_start,
                                                    const int2* __restrict__ csr2,
                                                    const float* __restrict__ dinv,
                                                    const float* __restrict__ bias,
                                                    ushort* __restrict__ Y,
                                                    float* __restrict__ bnsum,
                                                    float* __restrict__ bnss, int N) {
    int g = threadIdx.x >> 6, lane = threadIdx.x & 63;
    int d = lane * 2;
    float b0 = bias[d], b1 = bias[d + 1];
    float s0 = 0.f, s1 = 0.f, ss0 = 0.f, ss1 = 0.f;

    int nchunks = (N + 3) / 4;
    int wid = blockIdx.x * 4 + g;
    int nwaves = gridDim.x * 4;

    for (int chunk = wid; chunk < nchunks; chunk += nwaves) {
        int c = chunk * 4;
        int nn = min(4, N - c);

        // row_start[c..c+4] via one lane-load + shfl
        int rsv = row_start[c + min(lane, nn)];
        int rs0 = __shfl(rsv, 0);
        int rs1 = __shfl(rsv, min(1, nn));
        int rs2 = __shfl(rsv, min(2, nn));
        int rs3 = __shfl(rsv, min(3, nn));
        int rs4 = __shfl(rsv, nn);

        // dinv for the 4 nodes
        float dvv = dinv[c + min(lane, nn - 1)];
        float dv0 = __shfl(dvv, 0);
        float dv1 = __shfl(dvv, min(1, nn - 1));
        float dv2 = __shfl(dvv, min(2, nn - 1));
        float dv3 = __shfl(dvv, min(3, nn - 1));

        // self rows (prefetched up front)
        uint h0 = *(const uint*)&H[(size_t)c * 128 + d];
        uint h1 = (nn > 1) ? *(const uint*)&H[(size_t)(c + 1) * 128 + d] : 0u;
        uint h2 = (nn > 2) ? *(const uint*)&H[(size_t)(c + 2) * 128 + d] : 0u;
        uint h3 = (nn > 3) ? *(const uint*)&H[(size_t)(c + 3) * 128 + d] : 0u;

        float i0_0 = bflo(h0) * dv0 * dv0 + b0, i1_0 = bfhi(h0) * dv0 * dv0 + b1;
        float i0_1 = bflo(h1) * dv1 * dv1 + b0, i1_1 = bfhi(h1) * dv1 * dv1 + b1;
        float i0_2 = bflo(h2) * dv2 * dv2 + b0, i1_2 = bfhi(h2) * dv2 * dv2 + b1;
        float i0_3 = bflo(h3) * dv3 * dv3 + b0, i1_3 = bfhi(h3) * dv3 * dv3 + b1;

        int e0 = rs0, eend = rs4;
        int seg = 0;
        int nextb = rs1;
        float a0 = i0_0, a1 = i1_0;

        for (int base = e0; base < eend; base += 64) {
            int cnt = min(64, eend - base);
            int2 me = (lane < cnt) ? csr2[base + lane] : make_int2(0, 0);
            int sl = me.x;
            float nl = __int_as_float(me.y);

            for (int j = 0; j < cnt; j += 8) {
                int mm = min(8, cnt - j);
                uint v[8]; float nr[8];
                #pragma unroll
                for (int k = 0; k < 8; ++k) {
                    int idx = min(j + k, cnt - 1);
                    int sk = __shfl(sl, idx);
                    float nk = __shfl(nl, idx);
                    nr[k] = (k < mm) ? nk : 0.f;
                    v[k] = *(const uint*)&H[(size_t)sk * 128 + d];
                }
                #pragma unroll
                for (int k = 0; k < 8; ++k) {
                    if (k < mm) {
                        int e = base + j + k;
                        while (e >= nextb) {     // uniform boundary crossing
                            float r0 = fmaxf(a0, 0.f), r1 = fmaxf(a1, 0.f);
                            *(uint*)&Y[(size_t)(c + seg) * 128 + d] =
                                (uint)f2bf(r0) | ((uint)f2bf(r1) << 16);
                            s0 += r0; ss0 += r0 * r0; s1 += r1; ss1 += r1 * r1;
                            seg++;
                            a0 = sel4f(i0_0, i0_1, i0_2, i0_3, seg);
                            a1 = sel4f(i1_0, i1_1, i1_2, i1_3, seg);
                            nextb = sel4i(rs1, rs2, rs3, rs4, seg);
                        }
                        a0 += bflo(v[k]) * nr[k];
                        a1 += bfhi(v[k]) * nr[k];
                    }
                }
            }
        }
        // final flush: current seg + trailing (possibly empty) segs
        for (;;) {
            float r0 = fmaxf(a0, 0.f), r1 = fmaxf(a1, 0.f);
            *(uint*)&Y[(size_t)(c + seg) * 128 + d] = (uint)f2bf(r0) | ((uint)f2bf(r1) << 16);
            s0 += r0; ss0 += r0 * r0; s1 += r1; ss1 += r1 * r1;
            seg++;
            if (seg >= nn) break;
            a0 = sel4f(i0_0, i0_1, i0_2, i0_3, seg);
            a1 = sel4f(i1_0, i1_1, i1_2, i1_3, seg);
            nextb = sel4i(rs1, rs2, rs3, rs4, seg);
        }
    }

    __shared__ float red[4][128];
    red[g][d] = s0; red[g][d + 1] = s1;
    __syncthreads();
    if (g == 0) {
        atomicAdd(&bnsum[d],     red[0][d] + red[1][d] + red[2][d] + red[3][d]);
        atomicAdd(&bnsum[d + 1], red[0][d + 1] + red[1][d + 1] + red[2][d + 1] + red[3][d + 1]);
    }
    __syncthreads();
    red[g][d] = ss0; red[g][d + 1] = ss1;
    __syncthreads();
    if (g == 0) {
        atomicAdd(&bnss[d],     red[0][d] + red[1][d] + red[2][d] + red[3][d]);
        atomicAdd(&bnss[d + 1], red[0][d + 1] + red[1][d + 1] + red[2][d + 1] + red[3][d + 1]);
    }
}

// bnfinalize also re-zeroes the stat accumulators for the next layer
__global__ void bnfinalize(float* __restrict__ bnsum, float* __restrict__ bnss,
                           const float* __restrict__ gamma, const float* __restrict__ beta,
                           float* __restrict__ scale, float* __restrict__ shift, float invN) {
    int d = threadIdx.x;   // 128 threads
    float mu  = bnsum[d] * invN;
    float var = bnss[d] * invN - mu * mu;
    float sc  = gamma[d] * rsqrtf(var + 1e-5f);
    scale[d] = sc;
    shift[d] = beta[d] - mu * sc;
    bnsum[d] = 0.f;
    bnss[d] = 0.f;
}

// ---------------- Head ----------------

__global__ __launch_bounds__(256) void head_ls(const ushort* __restrict__ H,
                                               const float* __restrict__ W2t,  // [10][128]
                                               const float* __restrict__ b2,
                                               float* __restrict__ OUT, int N) {
    int wv = threadIdx.x >> 6, lane = threadIdx.x & 63;
    int row = blockIdx.x * 4 + wv;
    if (row >= N) return;
    uint hv = *(const uint*)&H[(size_t)row * 128 + lane * 2];
    float h0 = bflo(hv), h1 = bfhi(hv);
    float logit[10];
    #pragma unroll
    for (int c = 0; c < 10; ++c) {
        float2 w = *(const float2*)&W2t[c * 128 + lane * 2];
        float p = h0 * w.x + h1 * w.y;
        #pragma unroll
        for (int off = 32; off > 0; off >>= 1) p += __shfl_xor(p, off, 64);
        logit[c] = p + b2[c];
    }
    float m = logit[0];
    #pragma unroll
    for (int c = 1; c < 10; ++c) m = fmaxf(m, logit[c]);
    float sum = 0.f;
    #pragma unroll
    for (int c = 0; c < 10; ++c) sum += expf(logit[c] - m);
    float lse = m + logf(sum);
    if (lane < 10) OUT[(size_t)row * 10 + lane] = logit[lane] - lse;
}

// ---------------- Launch ----------------

static inline char* align16(char* p) { return (char*)(((uintptr_t)p + 15) & ~(uintptr_t)15); }

extern "C" void kernel_launch(void* const* d_in, const int* in_sizes, int n_in,
                              void* d_out, int out_size, void* d_ws, size_t ws_size,
                              hipStream_t stream) {
    const float* x    = (const float*)d_in[0];
    const int*   ei   = (const int*)d_in[1];
    const float* W1   = (const float*)d_in[2];
    const float* b1   = (const float*)d_in[3];
    const float* g1   = (const float*)d_in[4];
    const float* be1  = (const float*)d_in[5];
    const float* W2   = (const float*)d_in[6];
    const float* b2   = (const float*)d_in[7];
    const float* g2   = (const float*)d_in[8];
    const float* be2  = (const float*)d_in[9];
    const float* l1w  = (const float*)d_in[10];
    const float* l1b  = (const float*)d_in[11];
    const float* l2w  = (const float*)d_in[12];
    const float* l2b  = (const float*)d_in[13];
    float* out = (float*)d_out;

    int N = in_sizes[0] / 128;   // 50000
    int E = in_sizes[1] / 2;     // 640000
    const int* srcp = ei;
    const int* dstp = ei + E;

    char* w = (char*)d_ws;
    ushort* bufA  = (ushort*)w;  w = align16(w + (size_t)N * 128 * 2);
    ushort* bufB  = (ushort*)w;  w = align16(w + (size_t)N * 128 * 2);
    int*   degc   = (int*)w;     w += (size_t)N * 4;       // contiguous with bnsum/bnss
    float* bnsum  = (float*)w;   w += 128 * 4;
    float* bnss   = (float*)w;   w = align16(w + 128 * 4);
    float* dinv   = (float*)w;   w = align16(w + (size_t)N * 4);
    int*   row_st = (int*)w;     w = align16(w + (size_t)(N + 1) * 4);
    int*   cursor = (int*)w;     w = align16(w + (size_t)N * 4);
    int2*  csr2   = (int2*)w;    w = align16(w + (size_t)E * 8);
    float* scale  = (float*)w;   w = align16(w + 128 * 4);
    float* shift  = (float*)w;   w = align16(w + 128 * 4);
    float* w2t    = (float*)w;   w = align16(w + 1280 * 4);
    ushort* wt1   = (ushort*)w;  w = align16(w + 16384 * 2);
    ushort* wt2   = (ushort*)w;  w = align16(w + 16384 * 2);
    ushort* wt3   = (ushort*)w;  w = align16(w + 16384 * 2);

    int eg = (E + 255) / 256;
    int gemm_grid = (N + 63) / 64;
    int nchunks = (N + 3) / 4;
    int gather_grid = (nchunks + 11) / 12;   // ~3 chunks per wave, 4 waves/block

    // ---- CSR build + weight prep (one memset covers degc+bnsum+bnss) ----
    hipMemsetAsync(degc, 0, ((size_t)N + 256) * 4, stream);
    deg_count<<<eg, 256, 0, stream>>>(dstp, degc, E);
    scan_all<<<1, 1024, 0, stream>>>(degc, row_st, cursor, dinv, N);
    csr_fill<<<eg, 256, 0, stream>>>(srcp, dstp, dinv, cursor, csr2, E);
    prep_weights<<<192, 256, 0, stream>>>(W1, W2, l1w, l2w, wt1, wt2, wt3, w2t);

    // ---- layer 1 ----
    gemm_mfma<true, false, false, false><<<gemm_grid, 256, 0, stream>>>(x, nullptr, nullptr, wt1, nullptr, bufA, N);
    gather_fused<<<gather_grid, 256, 0, stream>>>(bufA, row_st, csr2, dinv, b1, bufB, bnsum, bnss, N);
    bnfinalize<<<1, 128, 0, stream>>>(bnsum, bnss, g1, be1, scale, shift, 1.0f / N);

    // ---- layer 2 ----
    gemm_mfma<false, true, false, false><<<gemm_grid, 256, 0, stream>>>(bufB, scale, shift, wt2, nullptr, bufA, N);
    gather_fused<<<gather_grid, 256, 0, stream>>>(bufA, row_st, csr2, dinv, b2, bufB, bnsum, bnss, N);
    bnfinalize<<<1, 128, 0, stream>>>(bnsum, bnss, g2, be2, scale, shift, 1.0f / N);

    // ---- head ----
    gemm_mfma<false, true, true, true><<<gemm_grid, 256, 0, stream>>>(bufB, scale, shift, wt3, l1b, bufA, N);
    head_ls<<<(N + 3) / 4, 256, 0, stream>>>(bufA, w2t, l2b, out, N);
}